// Round 2
// baseline (103.229 us; speedup 1.0000x reference)
//
#include <hip/hip_runtime.h>
#include <hip/hip_bf16.h>

// MinibatchDiscrimination: B=512, IN=512, OUT=64, KD=8 (fp32 in/out)
// out[i, 0:512] = x[i, :]
// out[i, 512+o] = sum_j exp(-sum_k |M[i,o,k] - M[j,o,k]|),  M = x @ T
//
// R2 plan:
//  K1 prep  : out fill (copy x, zero last 64 cols) + x->bf16 (xb, row-major i,k)
//             + T->bf16 transposed (Tt[n][k], k-contiguous for B-fragments)
//  K2 gemm  : MFMA 16x16x32 bf16, 1024 waves, one 16x16 C-tile per wave,
//             fragments straight from global (L2-resident), Mt fp32 [64][512][8]
//  K3 pairs : 512 blocks (o, j-chunk of 64) x 128 thr, 4 i's/thread -> VALU-bound
//             (~3.8 us floor), wave-uniform LDS broadcast reads, atomicAdd out.

#define B_   512
#define IN_  512
#define OUT_ 64
#define KD_  8
#define ROW_ (IN_ + OUT_)    // 576
#define ROW4_ (ROW_ / 4)     // 144

typedef short short8 __attribute__((ext_vector_type(8)));
typedef float f32x4  __attribute__((ext_vector_type(4)));

__device__ __forceinline__ unsigned short f2bf(float f) {
    unsigned u = __float_as_uint(f);
    unsigned r = (u + 0x7FFFu + ((u >> 16) & 1u)) >> 16;   // RNE
    return (unsigned short)r;
}

// ---------------- K1: fused prep -------------------------------------------
// blocks [0,288)   : fill out (73728 float4)
// blocks [288,544) : convert x -> xb bf16 (65536 float4 -> ushort4)
// blocks [544,800) : transpose-convert T -> Tt[n][k] bf16 (65536 ushort4 items)
__global__ __launch_bounds__(256)
void prep_kernel(const float* __restrict__ x, const float* __restrict__ T,
                 float* __restrict__ out, unsigned short* __restrict__ xb,
                 unsigned short* __restrict__ Tt) {
    int b = blockIdx.x, t = threadIdx.x;
    if (b < 288) {
        int v = b * 256 + t;                  // [0, 512*144)
        int i  = v / ROW4_;
        int c4 = v - i * ROW4_;
        float4 val = (c4 < IN_ / 4) ? ((const float4*)x)[i * (IN_ / 4) + c4]
                                    : make_float4(0.f, 0.f, 0.f, 0.f);
        ((float4*)out)[v] = val;
    } else if (b < 544) {
        int v = (b - 288) * 256 + t;          // [0, 65536)
        float4 f = ((const float4*)x)[v];
        ushort4 u;
        u.x = f2bf(f.x); u.y = f2bf(f.y); u.z = f2bf(f.z); u.w = f2bf(f.w);
        ((ushort4*)xb)[v] = u;
    } else {
        int v = (b - 544) * 256 + t;          // [0, 65536): n = v>>7, k4 = (v&127)*4
        int n  = v >> 7;
        int k4 = (v & 127) << 2;
        ushort4 u;
        u.x = f2bf(T[(k4 + 0) * 512 + n]);
        u.y = f2bf(T[(k4 + 1) * 512 + n]);
        u.z = f2bf(T[(k4 + 2) * 512 + n]);
        u.w = f2bf(T[(k4 + 3) * 512 + n]);
        ((ushort4*)Tt)[v] = u;                // Tt[n*512 + k4 .. +3]
    }
}

// ---------------- K2: MFMA GEMM --------------------------------------------
// C[i][oc] = sum_k xb[i][k] * Tt[oc][k]; 32x32 tiles of 16x16, wave-per-tile.
// A-frag: lane holds A[m=lane&15][k=quad*8+j]  (row-major xb -> contiguous 16B)
// B-frag: lane holds B[n=lane&15][k=quad*8+j]  (Tt n-major -> contiguous 16B)
// C/D   : value r of lane l -> C[m=(l>>4)*4+r][n=l&15]   (verified mapping)
__global__ __launch_bounds__(256)
void gemm_mfma_kernel(const unsigned short* __restrict__ xb,
                      const unsigned short* __restrict__ Tt,
                      float* __restrict__ Mt) {
    int lane = threadIdx.x & 63;
    int wid  = threadIdx.x >> 6;
    int W    = blockIdx.x * 4 + wid;        // [0, 1024)
    int i0   = (W >> 5) * 16;
    int n0   = (W & 31) * 16;
    int r = lane & 15;
    int q = lane >> 4;
    const unsigned short* pa = xb + (i0 + r) * 512 + q * 8;
    const unsigned short* pb = Tt + (n0 + r) * 512 + q * 8;
    f32x4 acc = {0.f, 0.f, 0.f, 0.f};
    #pragma unroll
    for (int kt = 0; kt < 16; ++kt) {
        short8 a = *(const short8*)(pa + kt * 32);
        short8 b = *(const short8*)(pb + kt * 32);
        acc = __builtin_amdgcn_mfma_f32_16x16x32_bf16(a, b, acc, 0, 0, 0);
    }
    #pragma unroll
    for (int rr = 0; rr < 4; ++rr) {
        int i  = i0 + q * 4 + rr;
        int oc = n0 + r;
        Mt[(oc >> 3) * (B_ * KD_) + i * KD_ + (oc & 7)] = acc[rr];
    }
}

// ---------------- K3: all-pairs L1 + exp ------------------------------------
// 512 blocks = (o, jc) with jc covering j in [jc*64, jc*64+64); 128 threads;
// each thread owns i = t, t+128, t+256, t+384. LDS stages the 64-row j-slice
// (2 KB); inner reads are wave-uniform -> broadcast, conflict-free.
__global__ __launch_bounds__(128)
void pairs_kernel(const float* __restrict__ Mt, float* __restrict__ out) {
    int b  = blockIdx.x;
    int o  = b >> 3;
    int jc = b & 7;
    int t  = threadIdx.x;

    __shared__ float s[64 * KD_];           // 2 KB
    const float4* src = (const float4*)(Mt + o * (B_ * KD_) + jc * 64 * KD_);
    ((float4*)s)[t] = src[t];               // 128 float4 = 512 floats
    __syncthreads();

    const float* base = Mt + o * (B_ * KD_);
    float mi[4][KD_];
    #pragma unroll
    for (int ii = 0; ii < 4; ++ii) {
        int i = t + ii * 128;
        float4 lo = *(const float4*)(base + i * KD_);
        float4 hi = *(const float4*)(base + i * KD_ + 4);
        mi[ii][0] = lo.x; mi[ii][1] = lo.y; mi[ii][2] = lo.z; mi[ii][3] = lo.w;
        mi[ii][4] = hi.x; mi[ii][5] = hi.y; mi[ii][6] = hi.z; mi[ii][7] = hi.w;
    }

    float acc[4] = {0.f, 0.f, 0.f, 0.f};
    #pragma unroll 2
    for (int j = 0; j < 64; ++j) {
        float sj[KD_];
        #pragma unroll
        for (int k = 0; k < KD_; ++k) sj[k] = s[j * KD_ + k];
        #pragma unroll
        for (int ii = 0; ii < 4; ++ii) {
            float d = 0.f;
            #pragma unroll
            for (int k = 0; k < KD_; ++k) d += fabsf(mi[ii][k] - sj[k]);
            acc[ii] += __expf(-d);
        }
    }
    #pragma unroll
    for (int ii = 0; ii < 4; ++ii) {
        int i = t + ii * 128;
        atomicAdd(&out[i * ROW_ + IN_ + o], acc[ii]);
    }
}

extern "C" void kernel_launch(void* const* d_in, const int* in_sizes, int n_in,
                              void* d_out, int out_size, void* d_ws, size_t ws_size,
                              hipStream_t stream) {
    const float* x = (const float*)d_in[0];   // [512, 512]
    const float* T = (const float*)d_in[1];   // [512, 64, 8]
    float* out = (float*)d_out;               // [512, 576]

    // ws layout: Mt fp32 [64][512][8] @0 (1 MB); xb bf16 @1 MB (512 KB);
    //            Tt bf16 @1.5 MB (512 KB)
    float*          Mt = (float*)d_ws;
    unsigned short* xb = (unsigned short*)((char*)d_ws + (1u << 20));
    unsigned short* Tt = (unsigned short*)((char*)d_ws + (1u << 20) + (1u << 19));

    prep_kernel<<<800, 256, 0, stream>>>(x, T, out, xb, Tt);
    gemm_mfma_kernel<<<256, 256, 0, stream>>>(xb, Tt, Mt);
    pairs_kernel<<<512, 128, 0, stream>>>(Mt, out);
}

// Round 3
// 97.451 us; speedup vs baseline: 1.0593x; 1.0593x over previous
//
#include <hip/hip_runtime.h>
#include <hip/hip_bf16.h>

// MinibatchDiscrimination: B=512, IN=512, OUT=64, KD=8 (fp32 in/out)
// out[i, 0:512] = x[i, :]
// out[i, 512+o] = sum_j exp(-sum_k |M[i,o,k] - M[j,o,k]|),  M = x @ T
//
// R3: prep with LDS-tiled T-transpose (was scattered scalar gather);
//     pairs with 8 i/thread + block-level LDS reduction (atomics 1M -> 256K);
//     gemm (MFMA 16x16x32 bf16, direct-from-global fragments) unchanged.

#define B_   512
#define IN_  512
#define OUT_ 64
#define KD_  8
#define ROW_ (IN_ + OUT_)    // 576
#define ROW4_ (ROW_ / 4)     // 144

typedef short short8 __attribute__((ext_vector_type(8)));
typedef float f32x4  __attribute__((ext_vector_type(4)));

__device__ __forceinline__ unsigned short f2bf(float f) {
    unsigned u = __float_as_uint(f);
    return (unsigned short)((u + 0x7FFFu + ((u >> 16) & 1u)) >> 16);   // RNE
}

// ---------------- K1: fused prep -------------------------------------------
// blocks [0,288)   : fill out rows (copy x, zero last 64 cols)
// blocks [288,544) : x -> xb bf16 (coalesced float4 -> ushort4)
// blocks [544,608) : T (512k x 512n) -> Tt bf16 [n][k] via LDS 64x64 tiles
__global__ __launch_bounds__(256)
void prep_kernel(const float* __restrict__ x, const float* __restrict__ T,
                 float* __restrict__ out, unsigned short* __restrict__ xb,
                 unsigned short* __restrict__ Tt) {
    int b = blockIdx.x, t = threadIdx.x;
    if (b < 288) {
        int v = b * 256 + t;                  // [0, 512*144)
        int i  = v / ROW4_;
        int c4 = v - i * ROW4_;
        float4 val = (c4 < IN_ / 4) ? ((const float4*)x)[i * (IN_ / 4) + c4]
                                    : make_float4(0.f, 0.f, 0.f, 0.f);
        ((float4*)out)[v] = val;
    } else if (b < 544) {
        int v = (b - 288) * 256 + t;          // [0, 65536)
        float4 f = ((const float4*)x)[v];
        ushort4 u;
        u.x = f2bf(f.x); u.y = f2bf(f.y); u.z = f2bf(f.z); u.w = f2bf(f.w);
        ((ushort4*)xb)[v] = u;
    } else {
        // 64 tiles of 64x64: tile = (ktile, ntile) over 8x8
        int tile = b - 544;
        int k0 = (tile >> 3) * 64;
        int n0 = (tile & 7) * 64;
        __shared__ float ts[64][65];          // +1 pad: <=2-way bank aliasing
        int r = t >> 4;            // 0..15
        int c = (t & 15) * 4;      // 0..60
        #pragma unroll
        for (int p = 0; p < 4; ++p) {
            const float* src = T + (k0 + r + p * 16) * 512 + n0 + c;
            float4 f = *(const float4*)src;
            ts[r + p * 16][c + 0] = f.x;
            ts[r + p * 16][c + 1] = f.y;
            ts[r + p * 16][c + 2] = f.z;
            ts[r + p * 16][c + 3] = f.w;
        }
        __syncthreads();
        #pragma unroll
        for (int p = 0; p < 4; ++p) {
            int n = (t >> 4) + p * 16;        // 0..63
            int k = (t & 15) * 4;             // 0..60
            ushort4 u;
            u.x = f2bf(ts[k + 0][n]);
            u.y = f2bf(ts[k + 1][n]);
            u.z = f2bf(ts[k + 2][n]);
            u.w = f2bf(ts[k + 3][n]);
            *(ushort4*)(Tt + (n0 + n) * 512 + k0 + k) = u;
        }
    }
}

// ---------------- K2: MFMA GEMM (unchanged from R2, verified) ---------------
__global__ __launch_bounds__(256)
void gemm_mfma_kernel(const unsigned short* __restrict__ xb,
                      const unsigned short* __restrict__ Tt,
                      float* __restrict__ Mt) {
    int lane = threadIdx.x & 63;
    int wid  = threadIdx.x >> 6;
    int W    = blockIdx.x * 4 + wid;        // [0, 1024)
    int i0   = (W >> 5) * 16;
    int n0   = (W & 31) * 16;
    int r = lane & 15;
    int q = lane >> 4;
    const unsigned short* pa = xb + (i0 + r) * 512 + q * 8;
    const unsigned short* pb = Tt + (n0 + r) * 512 + q * 8;
    f32x4 acc = {0.f, 0.f, 0.f, 0.f};
    #pragma unroll
    for (int kt = 0; kt < 16; ++kt) {
        short8 a = *(const short8*)(pa + kt * 32);
        short8 b = *(const short8*)(pb + kt * 32);
        acc = __builtin_amdgcn_mfma_f32_16x16x32_bf16(a, b, acc, 0, 0, 0);
    }
    #pragma unroll
    for (int rr = 0; rr < 4; ++rr) {
        int i  = i0 + q * 4 + rr;
        int oc = n0 + r;
        Mt[(oc >> 3) * (B_ * KD_) + i * KD_ + (oc & 7)] = acc[rr];
    }
}

// ---------------- K3: all-pairs L1 + exp ------------------------------------
// 512 blocks = (o, jc); jc covers j in [jc*64, jc*64+64). 256 threads = 4 waves,
// wave w handles the 16-j window j0 = jc*64 + w*16. Each thread owns 8 i's
// (i = lane + 64*ii). LDS j-slice reads are wave-uniform (broadcast).
// Block-level LDS reduction -> 512 global atomics per block (256K total).
__global__ __launch_bounds__(256)
void pairs_kernel(const float* __restrict__ Mt, float* __restrict__ out) {
    int b  = blockIdx.x;
    int o  = b >> 3;
    int jc = b & 7;
    int t    = threadIdx.x;
    int lane = t & 63;
    int w    = t >> 6;

    __shared__ float s[64 * KD_];           // 2 KB: the j-window rows
    __shared__ float s2[4][B_];             // 8 KB: per-wave partials
    const float* base = Mt + o * (B_ * KD_);
    if (t < 128)
        ((float4*)s)[t] = ((const float4*)(base + jc * 64 * KD_))[t];
    __syncthreads();

    float mi[8][KD_];
    #pragma unroll
    for (int ii = 0; ii < 8; ++ii) {
        const float* p = base + (lane + ii * 64) * KD_;
        float4 lo = *(const float4*)p;
        float4 hi = *(const float4*)(p + 4);
        mi[ii][0] = lo.x; mi[ii][1] = lo.y; mi[ii][2] = lo.z; mi[ii][3] = lo.w;
        mi[ii][4] = hi.x; mi[ii][5] = hi.y; mi[ii][6] = hi.z; mi[ii][7] = hi.w;
    }

    float acc[8] = {0.f, 0.f, 0.f, 0.f, 0.f, 0.f, 0.f, 0.f};
    int j0 = w * 16;
    #pragma unroll 2
    for (int jj = 0; jj < 16; ++jj) {
        const float* sj = s + (j0 + jj) * KD_;
        float v0 = sj[0], v1 = sj[1], v2 = sj[2], v3 = sj[3];
        float v4 = sj[4], v5 = sj[5], v6 = sj[6], v7 = sj[7];
        #pragma unroll
        for (int ii = 0; ii < 8; ++ii) {
            float d = fabsf(mi[ii][0] - v0) + fabsf(mi[ii][1] - v1)
                    + fabsf(mi[ii][2] - v2) + fabsf(mi[ii][3] - v3)
                    + fabsf(mi[ii][4] - v4) + fabsf(mi[ii][5] - v5)
                    + fabsf(mi[ii][6] - v6) + fabsf(mi[ii][7] - v7);
            acc[ii] += __expf(-d);
        }
    }

    #pragma unroll
    for (int ii = 0; ii < 8; ++ii)
        s2[w][lane + ii * 64] = acc[ii];
    __syncthreads();

    #pragma unroll
    for (int q = 0; q < 2; ++q) {
        int i = t * 2 + q;
        float v = s2[0][i] + s2[1][i] + s2[2][i] + s2[3][i];
        atomicAdd(&out[i * ROW_ + IN_ + o], v);
    }
}

extern "C" void kernel_launch(void* const* d_in, const int* in_sizes, int n_in,
                              void* d_out, int out_size, void* d_ws, size_t ws_size,
                              hipStream_t stream) {
    const float* x = (const float*)d_in[0];   // [512, 512]
    const float* T = (const float*)d_in[1];   // [512, 64, 8]
    float* out = (float*)d_out;               // [512, 576]

    float*          Mt = (float*)d_ws;                                  // 1 MB
    unsigned short* xb = (unsigned short*)((char*)d_ws + (1u << 20));   // 512 KB
    unsigned short* Tt = (unsigned short*)((char*)d_ws + (1u << 20) + (1u << 19));

    prep_kernel<<<608, 256, 0, stream>>>(x, T, out, xb, Tt);
    gemm_mfma_kernel<<<256, 256, 0, stream>>>(xb, Tt, Mt);
    pairs_kernel<<<512, 256, 0, stream>>>(Mt, out);
}

// Round 4
// 70.682 us; speedup vs baseline: 1.4605x; 1.3787x over previous
//
#include <hip/hip_runtime.h>

// MinibatchDiscrimination: B=512, IN=512, OUT=64, KD=8 (fp32 in/out)
// out[i, 0:512] = x[i, :]
// out[i, 512+o] = sum_j exp(-sum_k |M[i,o,k] - M[j,o,k]|),  M = x @ T
//
// R4: TWO kernels.
//  K1 gemm : grid 256 = (ib=8 i-tiles of 64) x (nb=32 n-tiles of 16).
//            Block stages its own 16x512 T-slice into LDS as bf16 (transpose
//            + convert fused, pad->conflict-free), A-frags read x fp32 from
//            global and convert in-reg. MFMA 16x16x32 bf16. Writes Mt[o][i][k].
//  K2 pairs: grid 256 = (o=64) x (ic=4 i-ranges of 128), 512 thr = 8 waves.
//            Block owns ALL j for its (o, i-range) -> exclusive final store,
//            no atomics, no out pre-zero. Full 16KB o-slice in LDS; wave w
//            handles j-window [w*64,w*64+64); 2 i/thread; wave-uniform LDS
//            reads broadcast. x->out copy folded in (hidden under VALU).

#define B_    512
#define IN_   512
#define OUT_  64
#define KD_   8
#define ROW_  576
#define ROW4_ 144

typedef short short8 __attribute__((ext_vector_type(8)));
typedef float f32x4  __attribute__((ext_vector_type(4)));

__device__ __forceinline__ unsigned short f2bf(float f) {
    // round-half-up truncation to bf16; exp(-d) suppression makes the
    // 0.4% relative error invisible (non-self d ~ 200, self-term exact 0)
    return (unsigned short)((__float_as_uint(f) + 0x8000u) >> 16);
}
__device__ __forceinline__ unsigned pack_bf2(float lo, float hi) {
    unsigned a = (__float_as_uint(lo) + 0x8000u) >> 16;
    unsigned b = (__float_as_uint(hi) + 0x8000u) & 0xFFFF0000u;
    return a | b;
}

// ---------------- K1: fused transpose + GEMM --------------------------------
__global__ __launch_bounds__(256)
void gemm_kernel(const float* __restrict__ x, const float* __restrict__ T,
                 float* __restrict__ Mt) {
    __shared__ unsigned short ts[16][520];   // [n-local][k], pad 520: 2-way max
    int t  = threadIdx.x;
    int bx = blockIdx.x;
    int nb = bx & 31, ib = bx >> 5;
    int n0 = nb * 16;

    // stage T[k][n0+c] -> ts[c][k] as bf16 (block-local transpose+convert)
    {
        int c  = t & 15;
        int kb = t >> 4;                     // 0..15
        #pragma unroll
        for (int p = 0; p < 32; ++p) {
            int k = kb + p * 16;
            ts[c][k] = f2bf(T[k * 512 + n0 + c]);
        }
    }
    __syncthreads();

    int lane = t & 63, wid = t >> 6;
    int r = lane & 15, q = lane >> 4;
    int i0 = ib * 64 + wid * 16;             // wave's 16-row i-tile
    const float* pa = x + (i0 + r) * 512 + q * 8;

    f32x4 acc = {0.f, 0.f, 0.f, 0.f};
    #pragma unroll
    for (int kt = 0; kt < 16; ++kt) {
        float4 f0 = *(const float4*)(pa + kt * 32);
        float4 f1 = *(const float4*)(pa + kt * 32 + 4);
        union { unsigned u[4]; short8 v; } A;
        A.u[0] = pack_bf2(f0.x, f0.y);
        A.u[1] = pack_bf2(f0.z, f0.w);
        A.u[2] = pack_bf2(f1.x, f1.y);
        A.u[3] = pack_bf2(f1.z, f1.w);
        short8 Bv = *(const short8*)&ts[r][q * 8 + kt * 32];
        acc = __builtin_amdgcn_mfma_f32_16x16x32_bf16(A.v, Bv, acc, 0, 0, 0);
    }

    // C/D map: row = q*4+rr, col = r  ->  i = i0+q*4+rr, oc = n0+r
    int oc = n0 + r;
    float* dst = Mt + (oc >> 3) * (B_ * KD_) + (oc & 7);
    #pragma unroll
    for (int rr = 0; rr < 4; ++rr)
        dst[(i0 + q * 4 + rr) * KD_] = acc[rr];
}

// ---------------- K2: all-pairs L1 + exp + x-copy ---------------------------
__global__ __launch_bounds__(512)
void pairs_kernel(const float* __restrict__ Mt, const float* __restrict__ x,
                  float* __restrict__ out) {
    __shared__ float s[B_ * KD_];            // 16 KB: full o-slice
    __shared__ float s2[8][128];             // 4 KB: per-wave partials
    int t  = threadIdx.x;
    int bx = blockIdx.x;
    int o  = bx >> 2;
    int ic = bx & 3;
    const float* base = Mt + o * (B_ * KD_);

    // stage the full slice (1024 float4 / 512 threads)
    ((float4*)s)[t]       = ((const float4*)base)[t];
    ((float4*)s)[t + 512] = ((const float4*)base)[t + 512];

    // side job: copy this block's share of x into out (cols 0..511)
    if (t < 256) {
        int v  = bx * 256 + t;               // [0, 65536)
        int i  = v >> 7;
        int c4 = v & 127;
        ((float4*)out)[i * ROW4_ + c4] = ((const float4*)x)[v];
    }

    int lane = t & 63, w = t >> 6;
    float mi[2][KD_];
    #pragma unroll
    for (int ii = 0; ii < 2; ++ii) {
        const float* p = base + (ic * 128 + lane + ii * 64) * KD_;
        float4 lo = *(const float4*)p;
        float4 hi = *(const float4*)(p + 4);
        mi[ii][0] = lo.x; mi[ii][1] = lo.y; mi[ii][2] = lo.z; mi[ii][3] = lo.w;
        mi[ii][4] = hi.x; mi[ii][5] = hi.y; mi[ii][6] = hi.z; mi[ii][7] = hi.w;
    }
    __syncthreads();

    float acc0 = 0.f, acc1 = 0.f;
    const float* sj = s + w * 64 * KD_;      // wave-uniform -> LDS broadcast
    #pragma unroll 4
    for (int jj = 0; jj < 64; ++jj) {
        float v0 = sj[0], v1 = sj[1], v2 = sj[2], v3 = sj[3];
        float v4 = sj[4], v5 = sj[5], v6 = sj[6], v7 = sj[7];
        sj += KD_;
        float d0 = fabsf(mi[0][0] - v0) + fabsf(mi[0][1] - v1)
                 + fabsf(mi[0][2] - v2) + fabsf(mi[0][3] - v3)
                 + fabsf(mi[0][4] - v4) + fabsf(mi[0][5] - v5)
                 + fabsf(mi[0][6] - v6) + fabsf(mi[0][7] - v7);
        float d1 = fabsf(mi[1][0] - v0) + fabsf(mi[1][1] - v1)
                 + fabsf(mi[1][2] - v2) + fabsf(mi[1][3] - v3)
                 + fabsf(mi[1][4] - v4) + fabsf(mi[1][5] - v5)
                 + fabsf(mi[1][6] - v6) + fabsf(mi[1][7] - v7);
        acc0 += __expf(-d0);
        acc1 += __expf(-d1);
    }
    s2[w][lane]      = acc0;
    s2[w][lane + 64] = acc1;
    __syncthreads();

    // exclusive final store: this block owns (o, i) for i in [ic*128, ic*128+128)
    if (t < 128) {
        float v = 0.f;
        #pragma unroll
        for (int ww = 0; ww < 8; ++ww) v += s2[ww][t];
        out[(ic * 128 + t) * ROW_ + IN_ + o] = v;
    }
}

extern "C" void kernel_launch(void* const* d_in, const int* in_sizes, int n_in,
                              void* d_out, int out_size, void* d_ws, size_t ws_size,
                              hipStream_t stream) {
    const float* x = (const float*)d_in[0];   // [512, 512]
    const float* T = (const float*)d_in[1];   // [512, 64, 8]
    float* out = (float*)d_out;               // [512, 576]
    float* Mt  = (float*)d_ws;                // [64][512][8] fp32, 1 MB

    gemm_kernel<<<256, 256, 0, stream>>>(x, T, Mt);
    pairs_kernel<<<256, 512, 0, stream>>>(Mt, x, out);
}